// Round 5
// baseline (391.649 us; speedup 1.0000x reference)
//
#include <hip/hip_runtime.h>
#include <stdint.h>

typedef __attribute__((ext_vector_type(8))) short bf16x8_t;   // 8 bf16 in 4 VGPRs
typedef __attribute__((ext_vector_type(4))) float f32x4_t;

#define DI __device__ __forceinline__

DI unsigned short f2b(float f) {
  union { float f; unsigned int u; } c; c.f = f;
  unsigned int u = c.u + 0x7FFFu + ((c.u >> 16) & 1u);   // RNE
  return (unsigned short)(u >> 16);
}
DI unsigned int pack2(float lo, float hi) {
  return (unsigned int)f2b(lo) | ((unsigned int)f2b(hi) << 16);
}
DI float b2f(unsigned short h) {
  union { unsigned int u; float f; } c; c.u = ((unsigned int)h) << 16;
  return c.f;
}
DI float silu_f(float z) { return z / (1.0f + __expf(-z)); }

// async global->LDS, 16B per lane; LDS dst = wave-uniform base + lane*16B
DI void load_lds16(const unsigned short* g, unsigned short* l) {
  __builtin_amdgcn_global_load_lds(
      (const __attribute__((address_space(1))) unsigned int*)g,
      (__attribute__((address_space(3))) unsigned int*)l,
      16, 0, 0);
}

// ---------------------------------------------------------------- transpose
DI float to_f(float v) { return v; }
DI float to_f(unsigned short v) { return b2f(v); }

template <typename T>
__global__ __launch_bounds__(256) void transpose_bf16(
    const T* __restrict__ in, unsigned short* __restrict__ out,
    int R, int C, long inZ, long outZ) {
  __shared__ float tile[32][33];
  const int tx = threadIdx.x, ty = threadIdx.y;
  const int c0 = blockIdx.x * 32, r0 = blockIdx.y * 32;
  in += (long)blockIdx.z * inZ;
  out += (long)blockIdx.z * outZ;
#pragma unroll
  for (int i = 0; i < 4; ++i)
    tile[ty + 8 * i][tx] = to_f(in[(long)(r0 + ty + 8 * i) * C + c0 + tx]);
  __syncthreads();
#pragma unroll
  for (int i = 0; i < 4; ++i)
    out[(long)(c0 + ty + 8 * i) * R + r0 + tx] = f2b(tile[tx][ty + 8 * i]);
}

// ---------------------------------------------------------------- layernorm
__global__ __launch_bounds__(256) void ln_kernel(
    const float* __restrict__ x, const float* __restrict__ g,
    const float* __restrict__ b, unsigned short* __restrict__ out) {
  __shared__ float red[8];
  const int row = blockIdx.x, tid = threadIdx.x;
  float4 v = ((const float4*)(x + (long)row * 1024))[tid];
  float s = v.x + v.y + v.z + v.w;
  float ss = v.x * v.x + v.y * v.y + v.z * v.z + v.w * v.w;
  for (int o = 32; o > 0; o >>= 1) { s += __shfl_down(s, o); ss += __shfl_down(ss, o); }
  const int wave = tid >> 6, lane = tid & 63;
  if (lane == 0) { red[wave * 2] = s; red[wave * 2 + 1] = ss; }
  __syncthreads();
  if (tid == 0) {
    float S = red[0] + red[2] + red[4] + red[6];
    float SS = red[1] + red[3] + red[5] + red[7];
    float mu = S * (1.0f / 1024.0f);
    float var = SS * (1.0f / 1024.0f) - mu * mu;
    red[0] = mu; red[1] = rsqrtf(var + 1e-5f);
  }
  __syncthreads();
  const float mu = red[0], rstd = red[1];
  float4 gg = ((const float4*)g)[tid];
  float4 bb = ((const float4*)b)[tid];
  ushort4 o;
  o.x = f2b((v.x - mu) * rstd * gg.x + bb.x);
  o.y = f2b((v.y - mu) * rstd * gg.y + bb.y);
  o.z = f2b((v.z - mu) * rstd * gg.z + bb.z);
  o.w = f2b((v.w - mu) * rstd * gg.w + bb.w);
  ((ushort4*)(out + (long)row * 1024))[tid] = o;
}

// ---------------------------------------------------------------- reduce 8 bf16 slabs -> bf16
// part layout: [b*8+s][262144 bf16]; out: [b][262144 bf16]
__global__ __launch_bounds__(256) void reduce_cvt(
    const unsigned short* __restrict__ part, unsigned short* __restrict__ out) {
  const int idx = blockIdx.x * 256 + threadIdx.x;   // over 4*65536 ushort4s
  const int b = idx >> 16, i = idx & 65535;
  float4 s = make_float4(0.f, 0.f, 0.f, 0.f);
#pragma unroll
  for (int sl = 0; sl < 8; ++sl) {
    ushort4 v = ((const ushort4*)part)[(long)(b * 8 + sl) * 65536 + i];
    s.x += b2f(v.x); s.y += b2f(v.y); s.z += b2f(v.z); s.w += b2f(v.w);
  }
  ushort4 o;
  o.x = f2b(s.x); o.y = f2b(s.y); o.z = f2b(s.z); o.w = f2b(s.w);
  ((ushort4*)out)[(long)b * 65536 + i] = o;
}

// ---------------------------------------------------------------- GEMM (BT)
enum { EPI_HSPLIT, EPI_ARELU, EPI_PART, EPI_QUADLIN, EPI_FINAL };

struct GemmP {
  const unsigned short* A;
  const unsigned short* B;
  const unsigned short* A2;   // QUADLIN phase-2
  const unsigned short* B2;
  int K, lda, ldb, ldc, mPerZ;
  long aZ, bZ;
  float scale;
  const float* bias;
  const float* bias2;
  const float* xres;
  const float* gamma;         // HSPLIT rope
  const float* beta;
  const unsigned short* gateIn;
  unsigned short* outU;
  unsigned short* gateOut;
  unsigned short* vTout;
  unsigned short* qqO;
  unsigned short* lqO;
  unsigned short* qkhO;
  unsigned short* lkTO;
  float* outF;
};

template <int EPI>
__global__ __launch_bounds__(256, 2) void gemm_bt(GemmP p) {
  constexpr bool kTrV = (EPI == EPI_HSPLIT);
  __shared__ unsigned short As[128 * 32];
  __shared__ unsigned short Bs[128 * 32];
  __shared__ unsigned int Cx[kTrV ? 128 * 68 : 1];  // padded C-tile scratch

  const int tid = threadIdx.x;
  const int lane = tid & 63;
  const int wave = tid >> 6;
  // grid-swap for L2 locality on the big GEMMs: block.x walks N, block.y walks M
  constexpr bool kSwap = (EPI == EPI_HSPLIT || EPI == EPI_FINAL);
  const int bx = kSwap ? blockIdx.y : blockIdx.x;
  const int by = kSwap ? blockIdx.x : blockIdx.y;
  const int z = blockIdx.z;

  unsigned short* lA = As + wave * 32 * 32;
  unsigned short* lB = Bs + wave * 32 * 32;
  const int wm = (wave & 1) * 64;
  const int wn = (wave >> 1) * 64;
  const int lm = lane & 15;
  const int kb = lane >> 4;
  const int rowSel = (wave * 32 + (lane >> 2));   // staging row within 128-tile
  const int colSel = (lane & 3) * 8;              // staging k-offset

  f32x4_t acc[4][4];
#pragma unroll
  for (int i = 0; i < 4; ++i)
#pragma unroll
    for (int j = 0; j < 4; ++j) acc[i][j] = (f32x4_t){0.f, 0.f, 0.f, 0.f};

  auto kloop = [&](const unsigned short* Ag, const unsigned short* Bg,
                   int lda, int ldb, int ksteps) {
    const int a16 = 16 * lda, b16 = 16 * ldb;
    for (int kt = 0; kt < ksteps; ++kt) {
      load_lds16(Ag, lA);
      load_lds16(Ag + a16, lA + 512);
      load_lds16(Bg, lB);
      load_lds16(Bg + b16, lB + 512);
      Ag += 32; Bg += 32;
      __syncthreads();
      bf16x8_t aF[4], bF[4];
#pragma unroll
      for (int i = 0; i < 4; ++i)
        aF[i] = *(const bf16x8_t*)(As + (wm + i * 16 + lm) * 32 + kb * 8);
#pragma unroll
      for (int j = 0; j < 4; ++j)
        bF[j] = *(const bf16x8_t*)(Bs + (wn + j * 16 + lm) * 32 + kb * 8);
#pragma unroll
      for (int i = 0; i < 4; ++i)
#pragma unroll
        for (int j = 0; j < 4; ++j)
          acc[i][j] = __builtin_amdgcn_mfma_f32_16x16x32_bf16(aF[i], bF[j], acc[i][j], 0, 0, 0);
      __syncthreads();
    }
  };

  if constexpr (EPI == EPI_QUADLIN) {
    const int b = z >> 3, g = z & 7;
    // phase 1: attn[z] (M=256 rows, K=256) @ vT[b][:, g*256:+256]
    kloop(p.A + (long)z * p.aZ + (long)(bx * 128 + rowSel) * 256 + colSel,
          p.B + (long)b * p.bZ + (long)(by * 128 + rowSel) * 2048 + g * 256 + colSel,
          256, 2048, 8);
    // phase 2: lin_q rows @ lkvT (K=128)
    kloop(p.A2 + ((long)z * 256 + bx * 128 + rowSel) * 128 + colSel,
          p.B2 + (long)b * 262144 + (long)(by * 128 + rowSel) * 128 + colSel,
          128, 128, 4);
  } else if constexpr (EPI == EPI_PART) {
    const int b = z >> 3, s = z & 7;   // split-K: 8 slices of 256
    kloop(p.A + (long)b * p.aZ + s * 256 + (long)(bx * 128 + rowSel) * p.lda + colSel,
          p.B + (long)b * p.bZ + s * 256 + (long)(by * 128 + rowSel) * p.ldb + colSel,
          p.lda, p.ldb, p.K >> 5);
  } else {
    kloop(p.A + (long)z * p.aZ + (long)(bx * 128 + rowSel) * p.lda + colSel,
          p.B + (long)z * p.bZ + (long)(by * 128 + rowSel) * p.ldb + colSel,
          p.lda, p.ldb, p.K >> 5);
  }

  // ---------------- epilogue ----------------
  if constexpr (EPI == EPI_HSPLIT) {
    if (by < 16) {
      // v half: silu, pack, LDS-transpose, coalesced store into vT[b][e][n]
#pragma unroll
      for (int i = 0; i < 4; ++i) {
        const int m_l = wm + i * 16 + (lane >> 4) * 4;
#pragma unroll
        for (int j = 0; j < 4; ++j) {
          const int e_l = wn + j * 16 + lm;
          const float bb = p.bias[by * 128 + e_l];
          const float s0 = silu_f(acc[i][j][0] + bb);
          const float s1 = silu_f(acc[i][j][1] + bb);
          const float s2 = silu_f(acc[i][j][2] + bb);
          const float s3 = silu_f(acc[i][j][3] + bb);
          Cx[e_l * 68 + (m_l >> 1)] = pack2(s0, s1);
          Cx[e_l * 68 + (m_l >> 1) + 1] = pack2(s2, s3);
        }
      }
      __syncthreads();
      const int b = bx >> 4;
      const int n0 = (bx & 15) * 128;
      unsigned short* dst = p.vTout + ((long)b * 2048 + by * 128) * 2048 + n0;
#pragma unroll
      for (int rep = 0; rep < 8; ++rep) {
        const int flat = rep * 256 + tid;
        const int e_l = flat >> 4, q = flat & 15;
        uint4 val = *(const uint4*)(Cx + e_l * 68 + q * 4);
        *(uint4*)(dst + (long)e_l * 2048 + q * 8) = val;
      }
    } else if (by < 32) {
      // gate half
#pragma unroll
      for (int i = 0; i < 4; ++i) {
        const int row0 = bx * 128 + wm + i * 16 + (lane >> 4) * 4;
#pragma unroll
        for (int j = 0; j < 4; ++j) {
          const int col = by * 128 + wn + j * 16 + lm;   // 2048..4095
          const float bb = p.bias[col];
#pragma unroll
          for (int r = 0; r < 4; ++r)
            p.gateOut[(long)(row0 + r) * 2048 + col - 2048] =
                f2b(silu_f(acc[i][j][r] + bb));
        }
      }
    } else {
      // qk block (all 128 qk dims in this by): silu -> LDS -> OffsetScale+RoPE
      unsigned short* q16 = (unsigned short*)Cx;   // [128][136] bf16
#pragma unroll
      for (int i = 0; i < 4; ++i) {
        const int rloc = wm + i * 16 + (lane >> 4) * 4;
#pragma unroll
        for (int j = 0; j < 4; ++j) {
          const int cl = wn + j * 16 + lm;         // 0..127
          const float bb = p.bias2[cl];
#pragma unroll
          for (int r = 0; r < 4; ++r)
            q16[(rloc + r) * 136 + cl] = f2b(silu_f(acc[i][j][r] + bb));
        }
      }
      __syncthreads();
      const int j = tid & 63;
      const int rq = tid >> 6;
      const float freq = powf(10000.0f, (float)j * (1.0f / 64.0f));
      float ga[4], gb[4], ea[4], eb[4];
#pragma unroll
      for (int h = 0; h < 4; ++h) {
        ga[h] = p.gamma[h * 128 + j];  gb[h] = p.gamma[h * 128 + 64 + j];
        ea[h] = p.beta[h * 128 + j];   eb[h] = p.beta[h * 128 + 64 + j];
      }
      unsigned short* outs[3] = {p.qqO, p.lqO, p.qkhO};
      for (int rr = 0; rr < 32; ++rr) {
        const int row = rr * 4 + rq;
        const float x1 = b2f(q16[row * 136 + j]);
        const float x2 = b2f(q16[row * 136 + 64 + j]);
        const int t = bx * 128 + row;
        const int pos = t & 2047, bidx = t >> 11;
        const float ang = (float)pos * freq;
        const float sn = sinf(ang), cs = cosf(ang);
#pragma unroll
        for (int h = 0; h < 3; ++h) {
          const float y1 = x1 * ga[h] + ea[h], y2 = x2 * gb[h] + eb[h];
          outs[h][(long)t * 128 + j] = f2b(y1 * cs - y2 * sn);
          outs[h][(long)t * 128 + 64 + j] = f2b(y2 * cs + y1 * sn);
        }
        const float y1 = x1 * ga[3] + ea[3], y2 = x2 * gb[3] + eb[3];
        p.lkTO[((long)bidx * 128 + j) * 2048 + pos] = f2b(y1 * cs - y2 * sn);
        p.lkTO[((long)bidx * 128 + 64 + j) * 2048 + pos] = f2b(y2 * cs + y1 * sn);
      }
    }
  } else {
#pragma unroll
    for (int i = 0; i < 4; ++i) {
      const int row0 = bx * 128 + wm + i * 16 + (lane >> 4) * 4;
      long rowg0;
      if constexpr (EPI == EPI_PART) rowg0 = row0;           // within-slab row
      else rowg0 = (long)z * p.mPerZ + row0;
#pragma unroll
      for (int j = 0; j < 4; ++j) {
        const int col = by * 128 + wn + j * 16 + lm;
        if constexpr (EPI == EPI_ARELU) {
#pragma unroll
          for (int r = 0; r < 4; ++r) {
            float s = acc[i][j][r] * p.scale;
            s = s > 0.f ? s : 0.f;
            p.outU[(rowg0 + r) * (long)p.ldc + col] = f2b(s * s);
          }
        } else if constexpr (EPI == EPI_PART) {
          unsigned short* slab = p.outU + (long)z * 262144;  // z = b*8+s
#pragma unroll
          for (int r = 0; r < 4; ++r)
            slab[(rowg0 + r) * (long)p.ldc + col] = f2b(acc[i][j][r] * p.scale);
        } else if constexpr (EPI == EPI_QUADLIN) {
#pragma unroll
          for (int r = 0; r < 4; ++r) {
            const long idx = (rowg0 + r) * (long)p.ldc + col;
            p.outU[idx] = f2b(b2f(p.gateIn[idx]) * acc[i][j][r]);
          }
        } else {  // EPI_FINAL: + b_out + x residual, fp32 out
          const float bb = p.bias[col];
#pragma unroll
          for (int r = 0; r < 4; ++r) {
            const long idx = (rowg0 + r) * (long)p.ldc + col;
            p.outF[idx] = acc[i][j][r] + bb + p.xres[idx];
          }
        }
      }
    }
  }
}

// ---------------------------------------------------------------- launch
extern "C" void kernel_launch(void* const* d_in, const int* in_sizes, int n_in,
                              void* d_out, int out_size, void* d_ws, size_t ws_size,
                              hipStream_t stream) {
  const float* x        = (const float*)d_in[0];
  const float* ln_g     = (const float*)d_in[1];
  const float* ln_b     = (const float*)d_in[2];
  const float* W_hidden = (const float*)d_in[3];
  const float* b_hidden = (const float*)d_in[4];
  const float* W_qk     = (const float*)d_in[5];
  const float* b_qk     = (const float*)d_in[6];
  const float* os_gamma = (const float*)d_in[7];
  const float* os_beta  = (const float*)d_in[8];
  const float* W_out    = (const float*)d_in[9];
  const float* b_out    = (const float*)d_in[10];
  float* out = (float*)d_out;

  char* w = (char*)d_ws;
  auto ws = [&](size_t bytes) { char* p = w; w += bytes; return (unsigned short*)p; };
  unsigned short* WT     = ws(8650752);   // [4224][1024] bf16 (Wh cols | Wqk cols)
  unsigned short* WoT    = ws(4194304);   // [1024][2048]
  unsigned short* normed = ws(16777216);  // [8192][1024]
  unsigned short* vT     = ws(33554432);  // [4][2048 e][2048 n]
  unsigned short* gate   = ws(33554432);  // [8192][2048]
  unsigned short* qq     = ws(2097152);
  unsigned short* qkh    = ws(2097152);
  unsigned short* lq     = ws(2097152);
  unsigned short* lkT    = ws(2097152);   // [4][128][2048]
  unsigned short* attn   = ws(4194304);   // [32][256][256]
  unsigned short* lkvP   = ws(16777216);  // [32 slabs][2048][128] bf16 partials
  unsigned short* lkvT   = ws(2097152);   // [4][2048 e][128 d] bf16
  unsigned short* A3     = ws(33554432);  // [8192][2048]

  dim3 tb(32, 8);
  transpose_bf16<float><<<dim3(128, 32, 1), tb, 0, stream>>>(W_hidden, WT, 1024, 4096, 0, 0);
  transpose_bf16<float><<<dim3(4, 32, 1), tb, 0, stream>>>(W_qk, WT + 4096 * 1024, 1024, 128, 0, 0);
  transpose_bf16<float><<<dim3(32, 64, 1), tb, 0, stream>>>(W_out, WoT, 2048, 1024, 0, 0);
  ln_kernel<<<8192, 256, 0, stream>>>(x, ln_g, ln_b, normed);

  {  // GEMM1: [v->vT | gate | qk->rope(qq,lq,qkh,lkT)] = silu(normed @ [Wh|Wqk] + b)
    GemmP p{}; p.A = normed; p.B = WT; p.K = 1024; p.lda = 1024; p.ldb = 1024;
    p.bias = b_hidden; p.bias2 = b_qk;
    p.gamma = os_gamma; p.beta = os_beta;
    p.vTout = vT; p.gateOut = gate;
    p.qqO = qq; p.lqO = lq; p.qkhO = qkh; p.lkTO = lkT;
    gemm_bt<EPI_HSPLIT><<<dim3(33, 64, 1), 256, 0, stream>>>(p);  // x=N, y=M
  }
  {  // sim -> attn = relu(sim/256)^2, per (b,g)
    GemmP p{}; p.A = qq; p.B = qkh; p.K = 128; p.lda = 128; p.ldb = 128;
    p.ldc = 256; p.mPerZ = 256; p.aZ = 32768; p.bZ = 32768;
    p.scale = 1.f / 256.f; p.outU = attn;
    gemm_bt<EPI_ARELU><<<dim3(2, 2, 32), 256, 0, stream>>>(p);
  }
  {  // lin_kv partials: slab[z=b*8+s][e][d] = vT[b][e][sK] @ lkT[b][d][sK] / 2048
    GemmP p{}; p.A = vT; p.B = lkT; p.K = 256; p.lda = 2048; p.ldb = 2048;
    p.ldc = 128; p.mPerZ = 2048; p.aZ = 4194304; p.bZ = 262144;
    p.scale = 1.f / 2048.f; p.outU = lkvP;
    gemm_bt<EPI_PART><<<dim3(16, 1, 32), 256, 0, stream>>>(p);
  }
  reduce_cvt<<<1024, 256, 0, stream>>>(lkvP, lkvT);
  {  // A3 = gate * (attn @ vg + lin_q @ lin_kv)   (two-phase K)
    GemmP p{}; p.A = attn; p.B = vT; p.A2 = lq; p.B2 = lkvT;
    p.ldc = 2048; p.mPerZ = 256; p.aZ = 65536; p.bZ = 4194304;
    p.gateIn = gate; p.outU = A3;
    gemm_bt<EPI_QUADLIN><<<dim3(2, 16, 32), 256, 0, stream>>>(p);
  }
  {  // out = A3 @ W_out + b_out + x
    GemmP p{}; p.A = A3; p.B = WoT; p.K = 2048; p.lda = 2048; p.ldb = 2048;
    p.ldc = 1024; p.mPerZ = 0; p.bias = b_out; p.xres = x; p.outF = out;
    gemm_bt<EPI_FINAL><<<dim3(8, 64, 1), 256, 0, stream>>>(p);  // x=N, y=M
  }
}

// Round 6
// 374.781 us; speedup vs baseline: 1.0450x; 1.0450x over previous
//
#include <hip/hip_runtime.h>
#include <stdint.h>

typedef __attribute__((ext_vector_type(8))) short bf16x8_t;   // 8 bf16 in 4 VGPRs
typedef __attribute__((ext_vector_type(4))) float f32x4_t;

#define DI __device__ __forceinline__

DI unsigned short f2b(float f) {
  union { float f; unsigned int u; } c; c.f = f;
  unsigned int u = c.u + 0x7FFFu + ((c.u >> 16) & 1u);   // RNE
  return (unsigned short)(u >> 16);
}
DI unsigned int pack2(float lo, float hi) {
  return (unsigned int)f2b(lo) | ((unsigned int)f2b(hi) << 16);
}
DI float b2f(unsigned short h) {
  union { unsigned int u; float f; } c; c.u = ((unsigned int)h) << 16;
  return c.f;
}
DI float silu_f(float z) { return z / (1.0f + __expf(-z)); }

// async global->LDS, 16B per lane; LDS dst = wave-uniform base + lane*16B
DI void load_lds16(const unsigned short* g, unsigned short* l) {
  __builtin_amdgcn_global_load_lds(
      (const __attribute__((address_space(1))) unsigned int*)g,
      (__attribute__((address_space(3))) unsigned int*)l,
      16, 0, 0);
}

// ---------------------------------------------------------------- prep mega-kernel
// flat grid: [0,4096) W_hidden T | [4096,6144) W_out T | [6144,6272) W_qk T |
//            [6272,14464) LayerNorm rows
struct PrepP {
  const float *Wh, *Wo, *Wqk, *x, *g, *b;
  unsigned short *WT, *WoT, *normed;
};

__global__ __launch_bounds__(256) void prep_kernel(PrepP p) {
  const int blk = blockIdx.x;
  const int tx = threadIdx.x & 31, ty = threadIdx.x >> 5;
  if (blk < 6272) {
    const float* in; unsigned short* out; int R, C, gx;
    if (blk < 4096)      { in = p.Wh;  out = p.WT;                 R = 1024; C = 4096; gx = blk; }
    else if (blk < 6144) { in = p.Wo;  out = p.WoT;                R = 2048; C = 1024; gx = blk - 4096; }
    else                 { in = p.Wqk; out = p.WT + 4096 * 1024;   R = 1024; C = 128;  gx = blk - 6144; }
    const int xTiles = C >> 5;
    const int c0 = (gx % xTiles) * 32, r0 = (gx / xTiles) * 32;
    __shared__ float tile[32][33];
#pragma unroll
    for (int i = 0; i < 4; ++i)
      tile[ty + 8 * i][tx] = in[(long)(r0 + ty + 8 * i) * C + c0 + tx];
    __syncthreads();
#pragma unroll
    for (int i = 0; i < 4; ++i)
      out[(long)(c0 + ty + 8 * i) * R + r0 + tx] = f2b(tile[tx][ty + 8 * i]);
  } else {
    const int row = blk - 6272, tid = threadIdx.x;
    __shared__ float red[8];
    float4 v = ((const float4*)(p.x + (long)row * 1024))[tid];
    float s = v.x + v.y + v.z + v.w;
    float ss = v.x * v.x + v.y * v.y + v.z * v.z + v.w * v.w;
    for (int o = 32; o > 0; o >>= 1) { s += __shfl_down(s, o); ss += __shfl_down(ss, o); }
    const int wave = tid >> 6, lane = tid & 63;
    if (lane == 0) { red[wave * 2] = s; red[wave * 2 + 1] = ss; }
    __syncthreads();
    if (tid == 0) {
      float S = red[0] + red[2] + red[4] + red[6];
      float SS = red[1] + red[3] + red[5] + red[7];
      float mu = S * (1.0f / 1024.0f);
      float var = SS * (1.0f / 1024.0f) - mu * mu;
      red[0] = mu; red[1] = rsqrtf(var + 1e-5f);
    }
    __syncthreads();
    const float mu = red[0], rstd = red[1];
    float4 gg = ((const float4*)p.g)[tid];
    float4 bb = ((const float4*)p.b)[tid];
    ushort4 o;
    o.x = f2b((v.x - mu) * rstd * gg.x + bb.x);
    o.y = f2b((v.y - mu) * rstd * gg.y + bb.y);
    o.z = f2b((v.z - mu) * rstd * gg.z + bb.z);
    o.w = f2b((v.w - mu) * rstd * gg.w + bb.w);
    ((ushort4*)(p.normed + (long)row * 1024))[tid] = o;
  }
}

// ---------------------------------------------------------------- reduce 8 bf16 slabs -> bf16
__global__ __launch_bounds__(256) void reduce_cvt(
    const unsigned short* __restrict__ part, unsigned short* __restrict__ out) {
  const int idx = blockIdx.x * 256 + threadIdx.x;   // over 4*65536 ushort4s
  const int b = idx >> 16, i = idx & 65535;
  float4 s = make_float4(0.f, 0.f, 0.f, 0.f);
#pragma unroll
  for (int sl = 0; sl < 8; ++sl) {
    ushort4 v = ((const ushort4*)part)[(long)(b * 8 + sl) * 65536 + i];
    s.x += b2f(v.x); s.y += b2f(v.y); s.z += b2f(v.z); s.w += b2f(v.w);
  }
  ushort4 o;
  o.x = f2b(s.x); o.y = f2b(s.y); o.z = f2b(s.z); o.w = f2b(s.w);
  ((ushort4*)out)[(long)b * 65536 + i] = o;
}

// ---------------------------------------------------------------- GEMM (BT)
enum { EPI_HSPLIT, EPI_ARELU, EPI_PART, EPI_QUADLIN, EPI_FINAL };

struct GemmP {
  const unsigned short* A;
  const unsigned short* B;
  const unsigned short* A2;   // QUADLIN phase-2
  const unsigned short* B2;
  int K, lda, ldb, ldc, mPerZ;
  long aZ, bZ;
  float scale;
  const float* bias;
  const float* bias2;
  const float* xres;
  const float* gamma;         // HSPLIT rope
  const float* beta;
  const unsigned short* gateIn;
  unsigned short* outU;
  unsigned short* gateOut;
  unsigned short* vTout;
  unsigned short* qqO;
  unsigned short* lqO;
  unsigned short* qkhO;
  unsigned short* lkTO;
  float* outF;
};

template <int EPI>
__global__ __launch_bounds__(256, 2) void gemm_bt(GemmP p) {
  constexpr bool kTrV = (EPI == EPI_HSPLIT);
  // K-loop staging (16KB) aliased with epilogue C-tile scratch (34816B HSPLIT)
  constexpr int LDSB = kTrV ? (128 * 68 * 4) : 16384;
  __shared__ __align__(16) unsigned char lds_raw[LDSB];
  unsigned short* As = (unsigned short*)lds_raw;
  unsigned short* Bs = As + 128 * 32;
  unsigned int* Cx = (unsigned int*)lds_raw;

  const int tid = threadIdx.x;
  const int lane = tid & 63;
  const int wave = tid >> 6;
  const int bx = blockIdx.x, by = blockIdx.y, z = blockIdx.z;

  unsigned short* lA = As + wave * 32 * 32;
  unsigned short* lB = Bs + wave * 32 * 32;
  const int wm = (wave & 1) * 64;
  const int wn = (wave >> 1) * 64;
  const int lm = lane & 15;
  const int kb = lane >> 4;
  const int rowSel = (wave * 32 + (lane >> 2));   // staging row within 128-tile
  const int colSel = (lane & 3) * 8;              // staging k-offset

  f32x4_t acc[4][4];
#pragma unroll
  for (int i = 0; i < 4; ++i)
#pragma unroll
    for (int j = 0; j < 4; ++j) acc[i][j] = (f32x4_t){0.f, 0.f, 0.f, 0.f};

  auto kloop = [&](const unsigned short* Ag, const unsigned short* Bg,
                   int lda, int ldb, int ksteps) {
    const int a16 = 16 * lda, b16 = 16 * ldb;
    for (int kt = 0; kt < ksteps; ++kt) {
      load_lds16(Ag, lA);
      load_lds16(Ag + a16, lA + 512);
      load_lds16(Bg, lB);
      load_lds16(Bg + b16, lB + 512);
      Ag += 32; Bg += 32;
      __syncthreads();
      bf16x8_t aF[4], bF[4];
#pragma unroll
      for (int i = 0; i < 4; ++i)
        aF[i] = *(const bf16x8_t*)(As + (wm + i * 16 + lm) * 32 + kb * 8);
#pragma unroll
      for (int j = 0; j < 4; ++j)
        bF[j] = *(const bf16x8_t*)(Bs + (wn + j * 16 + lm) * 32 + kb * 8);
#pragma unroll
      for (int i = 0; i < 4; ++i)
#pragma unroll
        for (int j = 0; j < 4; ++j)
          acc[i][j] = __builtin_amdgcn_mfma_f32_16x16x32_bf16(aF[i], bF[j], acc[i][j], 0, 0, 0);
      __syncthreads();
    }
  };

  if constexpr (EPI == EPI_QUADLIN) {
    const int b = z >> 3, g = z & 7;
    // phase 1: attn[z] (M=256 rows, K=256) @ vT[b][:, g*256:+256]
    kloop(p.A + (long)z * p.aZ + (long)(bx * 128 + rowSel) * 256 + colSel,
          p.B + (long)b * p.bZ + (long)(by * 128 + rowSel) * 2048 + g * 256 + colSel,
          256, 2048, 8);
    // phase 2: lin_q rows @ lkvT (K=128)
    kloop(p.A2 + ((long)z * 256 + bx * 128 + rowSel) * 128 + colSel,
          p.B2 + (long)b * 262144 + (long)(by * 128 + rowSel) * 128 + colSel,
          128, 128, 4);
  } else if constexpr (EPI == EPI_PART) {
    const int b = z >> 3, s = z & 7;   // split-K: 8 slices of 256
    kloop(p.A + (long)b * p.aZ + s * 256 + (long)(bx * 128 + rowSel) * p.lda + colSel,
          p.B + (long)b * p.bZ + s * 256 + (long)(by * 128 + rowSel) * p.ldb + colSel,
          p.lda, p.ldb, p.K >> 5);
  } else {
    kloop(p.A + (long)z * p.aZ + (long)(bx * 128 + rowSel) * p.lda + colSel,
          p.B + (long)z * p.bZ + (long)(by * 128 + rowSel) * p.ldb + colSel,
          p.lda, p.ldb, p.K >> 5);
  }

  // ---------------- epilogue ----------------
  if constexpr (EPI == EPI_HSPLIT) {
    __syncthreads();   // ensure all waves done reading As/Bs before Cx overwrite
    if (by < 16) {
      // v half: silu, pack, LDS-transpose, coalesced store into vT[b][e][n]
#pragma unroll
      for (int i = 0; i < 4; ++i) {
        const int m_l = wm + i * 16 + (lane >> 4) * 4;
#pragma unroll
        for (int j = 0; j < 4; ++j) {
          const int e_l = wn + j * 16 + lm;
          const float bb = p.bias[by * 128 + e_l];
          const float s0 = silu_f(acc[i][j][0] + bb);
          const float s1 = silu_f(acc[i][j][1] + bb);
          const float s2 = silu_f(acc[i][j][2] + bb);
          const float s3 = silu_f(acc[i][j][3] + bb);
          Cx[e_l * 68 + (m_l >> 1)] = pack2(s0, s1);
          Cx[e_l * 68 + (m_l >> 1) + 1] = pack2(s2, s3);
        }
      }
      __syncthreads();
      const int b = bx >> 4;
      const int n0 = (bx & 15) * 128;
      unsigned short* dst = p.vTout + ((long)b * 2048 + by * 128) * 2048 + n0;
#pragma unroll
      for (int rep = 0; rep < 8; ++rep) {
        const int flat = rep * 256 + tid;
        const int e_l = flat >> 4, q = flat & 15;
        uint4 val = *(const uint4*)(Cx + e_l * 68 + q * 4);
        *(uint4*)(dst + (long)e_l * 2048 + q * 8) = val;
      }
    } else if (by < 32) {
      // gate half
#pragma unroll
      for (int i = 0; i < 4; ++i) {
        const int row0 = bx * 128 + wm + i * 16 + (lane >> 4) * 4;
#pragma unroll
        for (int j = 0; j < 4; ++j) {
          const int col = by * 128 + wn + j * 16 + lm;   // 2048..4095
          const float bb = p.bias[col];
#pragma unroll
          for (int r = 0; r < 4; ++r)
            p.gateOut[(long)(row0 + r) * 2048 + col - 2048] =
                f2b(silu_f(acc[i][j][r] + bb));
        }
      }
    } else {
      // qk block (all 128 qk dims): silu -> LDS -> OffsetScale+RoPE
      unsigned short* q16 = (unsigned short*)Cx;   // [128][136] bf16 = 34816B
#pragma unroll
      for (int i = 0; i < 4; ++i) {
        const int rloc = wm + i * 16 + (lane >> 4) * 4;
#pragma unroll
        for (int j = 0; j < 4; ++j) {
          const int cl = wn + j * 16 + lm;         // 0..127
          const float bb = p.bias2[cl];
#pragma unroll
          for (int r = 0; r < 4; ++r)
            q16[(rloc + r) * 136 + cl] = f2b(silu_f(acc[i][j][r] + bb));
        }
      }
      __syncthreads();
      const int j = tid & 63;
      const int rq = tid >> 6;
      const float freq = powf(10000.0f, (float)j * (1.0f / 64.0f));
      float ga[4], gb[4], ea[4], eb[4];
#pragma unroll
      for (int h = 0; h < 4; ++h) {
        ga[h] = p.gamma[h * 128 + j];  gb[h] = p.gamma[h * 128 + 64 + j];
        ea[h] = p.beta[h * 128 + j];   eb[h] = p.beta[h * 128 + 64 + j];
      }
      unsigned short* outs[3] = {p.qqO, p.lqO, p.qkhO};
      for (int rr = 0; rr < 32; ++rr) {
        const int row = rr * 4 + rq;
        const float x1 = b2f(q16[row * 136 + j]);
        const float x2 = b2f(q16[row * 136 + 64 + j]);
        const int t = bx * 128 + row;
        const int pos = t & 2047, bidx = t >> 11;
        const float ang = (float)pos * freq;
        const float sn = sinf(ang), cs = cosf(ang);
#pragma unroll
        for (int h = 0; h < 3; ++h) {
          const float y1 = x1 * ga[h] + ea[h], y2 = x2 * gb[h] + eb[h];
          outs[h][(long)t * 128 + j] = f2b(y1 * cs - y2 * sn);
          outs[h][(long)t * 128 + 64 + j] = f2b(y2 * cs + y1 * sn);
        }
        const float y1 = x1 * ga[3] + ea[3], y2 = x2 * gb[3] + eb[3];
        p.lkTO[((long)bidx * 128 + j) * 2048 + pos] = f2b(y1 * cs - y2 * sn);
        p.lkTO[((long)bidx * 128 + 64 + j) * 2048 + pos] = f2b(y2 * cs + y1 * sn);
      }
    }
  } else {
#pragma unroll
    for (int i = 0; i < 4; ++i) {
      const int row0 = bx * 128 + wm + i * 16 + (lane >> 4) * 4;
      long rowg0;
      if constexpr (EPI == EPI_PART) rowg0 = row0;           // within-slab row
      else rowg0 = (long)z * p.mPerZ + row0;
#pragma unroll
      for (int j = 0; j < 4; ++j) {
        const int col = by * 128 + wn + j * 16 + lm;
        if constexpr (EPI == EPI_ARELU) {
#pragma unroll
          for (int r = 0; r < 4; ++r) {
            float s = acc[i][j][r] * p.scale;
            s = s > 0.f ? s : 0.f;
            p.outU[(rowg0 + r) * (long)p.ldc + col] = f2b(s * s);
          }
        } else if constexpr (EPI == EPI_PART) {
          unsigned short* slab = p.outU + (long)z * 262144;  // z = b*8+s
#pragma unroll
          for (int r = 0; r < 4; ++r)
            slab[(rowg0 + r) * (long)p.ldc + col] = f2b(acc[i][j][r] * p.scale);
        } else if constexpr (EPI == EPI_QUADLIN) {
#pragma unroll
          for (int r = 0; r < 4; ++r) {
            const long idx = (rowg0 + r) * (long)p.ldc + col;
            p.outU[idx] = f2b(b2f(p.gateIn[idx]) * acc[i][j][r]);
          }
        } else {  // EPI_FINAL: + b_out + x residual, fp32 out
          const float bb = p.bias[col];
#pragma unroll
          for (int r = 0; r < 4; ++r) {
            const long idx = (rowg0 + r) * (long)p.ldc + col;
            p.outF[idx] = acc[i][j][r] + bb + p.xres[idx];
          }
        }
      }
    }
  }
}

// ---------------------------------------------------------------- launch
extern "C" void kernel_launch(void* const* d_in, const int* in_sizes, int n_in,
                              void* d_out, int out_size, void* d_ws, size_t ws_size,
                              hipStream_t stream) {
  const float* x        = (const float*)d_in[0];
  const float* ln_g     = (const float*)d_in[1];
  const float* ln_b     = (const float*)d_in[2];
  const float* W_hidden = (const float*)d_in[3];
  const float* b_hidden = (const float*)d_in[4];
  const float* W_qk     = (const float*)d_in[5];
  const float* b_qk     = (const float*)d_in[6];
  const float* os_gamma = (const float*)d_in[7];
  const float* os_beta  = (const float*)d_in[8];
  const float* W_out    = (const float*)d_in[9];
  const float* b_out    = (const float*)d_in[10];
  float* out = (float*)d_out;

  char* w = (char*)d_ws;
  auto ws = [&](size_t bytes) { char* p = w; w += bytes; return (unsigned short*)p; };
  unsigned short* WT     = ws(8650752);   // [4224][1024] bf16 (Wh cols | Wqk cols)
  unsigned short* WoT    = ws(4194304);   // [1024][2048]
  unsigned short* normed = ws(16777216);  // [8192][1024]
  unsigned short* vT     = ws(33554432);  // [4][2048 e][2048 n]
  unsigned short* gate   = ws(33554432);  // [8192][2048]
  unsigned short* qq     = ws(2097152);
  unsigned short* qkh    = ws(2097152);
  unsigned short* lq     = ws(2097152);
  unsigned short* lkT    = ws(2097152);   // [4][128][2048]
  unsigned short* attn   = ws(4194304);   // [32][256][256]
  unsigned short* lkvP   = ws(16777216);  // [32 slabs][2048][128] bf16 partials
  unsigned short* lkvT   = ws(2097152);   // [4][2048 e][128 d] bf16
  unsigned short* A3     = ws(33554432);  // [8192][2048]

  {  // weight transposes + layernorm in one dispatch
    PrepP p{W_hidden, W_out, W_qk, x, ln_g, ln_b, WT, WoT, normed};
    prep_kernel<<<14464, 256, 0, stream>>>(p);
  }
  {  // GEMM1: [v->vT | gate | qk->rope(qq,lq,qkh,lkT)] = silu(normed @ [Wh|Wqk] + b)
    GemmP p{}; p.A = normed; p.B = WT; p.K = 1024; p.lda = 1024; p.ldb = 1024;
    p.bias = b_hidden; p.bias2 = b_qk;
    p.gamma = os_gamma; p.beta = os_beta;
    p.vTout = vT; p.gateOut = gate;
    p.qqO = qq; p.lqO = lq; p.qkhO = qkh; p.lkTO = lkT;
    gemm_bt<EPI_HSPLIT><<<dim3(64, 33, 1), 256, 0, stream>>>(p);
  }
  {  // sim -> attn = relu(sim/256)^2, per (b,g)
    GemmP p{}; p.A = qq; p.B = qkh; p.K = 128; p.lda = 128; p.ldb = 128;
    p.ldc = 256; p.mPerZ = 256; p.aZ = 32768; p.bZ = 32768;
    p.scale = 1.f / 256.f; p.outU = attn;
    gemm_bt<EPI_ARELU><<<dim3(2, 2, 32), 256, 0, stream>>>(p);
  }
  {  // lin_kv partials: slab[z=b*8+s][e][d] = vT[b][e][sK] @ lkT[b][d][sK] / 2048
    GemmP p{}; p.A = vT; p.B = lkT; p.K = 256; p.lda = 2048; p.ldb = 2048;
    p.ldc = 128; p.mPerZ = 2048; p.aZ = 4194304; p.bZ = 262144;
    p.scale = 1.f / 2048.f; p.outU = lkvP;
    gemm_bt<EPI_PART><<<dim3(16, 1, 32), 256, 0, stream>>>(p);
  }
  reduce_cvt<<<1024, 256, 0, stream>>>(lkvP, lkvT);
  {  // A3 = gate * (attn @ vg + lin_q @ lin_kv)   (two-phase K)
    GemmP p{}; p.A = attn; p.B = vT; p.A2 = lq; p.B2 = lkvT;
    p.ldc = 2048; p.mPerZ = 256; p.aZ = 65536; p.bZ = 4194304;
    p.gateIn = gate; p.outU = A3;
    gemm_bt<EPI_QUADLIN><<<dim3(2, 16, 32), 256, 0, stream>>>(p);
  }
  {  // out = A3 @ W_out + b_out + x
    GemmP p{}; p.A = A3; p.B = WoT; p.K = 2048; p.lda = 2048; p.ldb = 2048;
    p.ldc = 1024; p.mPerZ = 0; p.bias = b_out; p.xres = x; p.outF = out;
    gemm_bt<EPI_FINAL><<<dim3(64, 8, 1), 256, 0, stream>>>(p);
  }
}

// Round 7
// 350.935 us; speedup vs baseline: 1.1160x; 1.0680x over previous
//
#include <hip/hip_runtime.h>
#include <stdint.h>

typedef __attribute__((ext_vector_type(8))) short bf16x8_t;   // 8 bf16 in 4 VGPRs
typedef __attribute__((ext_vector_type(4))) float f32x4_t;

#define DI __device__ __forceinline__

DI unsigned short f2b(float f) {
  union { float f; unsigned int u; } c; c.f = f;
  unsigned int u = c.u + 0x7FFFu + ((c.u >> 16) & 1u);   // RNE
  return (unsigned short)(u >> 16);
}
DI unsigned int pack2(float lo, float hi) {
  return (unsigned int)f2b(lo) | ((unsigned int)f2b(hi) << 16);
}
DI float b2f(unsigned short h) {
  union { unsigned int u; float f; } c; c.u = ((unsigned int)h) << 16;
  return c.f;
}
DI float silu_f(float z) { return z / (1.0f + __expf(-z)); }

// async global->LDS, 16B per lane; LDS dst = wave-uniform base + lane*16B
DI void load_lds16(const unsigned short* g, unsigned short* l) {
  __builtin_amdgcn_global_load_lds(
      (const __attribute__((address_space(1))) unsigned int*)g,
      (__attribute__((address_space(3))) unsigned int*)l,
      16, 0, 0);
}

// ---------------------------------------------------------------- prep mega-kernel
// flat grid: [0,4096) W_hidden T | [4096,6144) W_out T | [6144,6272) W_qk T |
//            [6272,14464) LayerNorm rows
struct PrepP {
  const float *Wh, *Wo, *Wqk, *x, *g, *b;
  unsigned short *WT, *WoT, *normed;
};

__global__ __launch_bounds__(256) void prep_kernel(PrepP p) {
  const int blk = blockIdx.x;
  const int tx = threadIdx.x & 31, ty = threadIdx.x >> 5;
  if (blk < 6272) {
    const float* in; unsigned short* out; int R, C, gx;
    if (blk < 4096)      { in = p.Wh;  out = p.WT;                 R = 1024; C = 4096; gx = blk; }
    else if (blk < 6144) { in = p.Wo;  out = p.WoT;                R = 2048; C = 1024; gx = blk - 4096; }
    else                 { in = p.Wqk; out = p.WT + 4096 * 1024;   R = 1024; C = 128;  gx = blk - 6144; }
    const int xTiles = C >> 5;
    const int c0 = (gx % xTiles) * 32, r0 = (gx / xTiles) * 32;
    __shared__ float tile[32][33];
#pragma unroll
    for (int i = 0; i < 4; ++i)
      tile[ty + 8 * i][tx] = in[(long)(r0 + ty + 8 * i) * C + c0 + tx];
    __syncthreads();
#pragma unroll
    for (int i = 0; i < 4; ++i)
      out[(long)(c0 + ty + 8 * i) * R + r0 + tx] = f2b(tile[tx][ty + 8 * i]);
  } else {
    const int row = blk - 6272, tid = threadIdx.x;
    __shared__ float red[8];
    float4 v = ((const float4*)(p.x + (long)row * 1024))[tid];
    float s = v.x + v.y + v.z + v.w;
    float ss = v.x * v.x + v.y * v.y + v.z * v.z + v.w * v.w;
    for (int o = 32; o > 0; o >>= 1) { s += __shfl_down(s, o); ss += __shfl_down(ss, o); }
    const int wave = tid >> 6, lane = tid & 63;
    if (lane == 0) { red[wave * 2] = s; red[wave * 2 + 1] = ss; }
    __syncthreads();
    if (tid == 0) {
      float S = red[0] + red[2] + red[4] + red[6];
      float SS = red[1] + red[3] + red[5] + red[7];
      float mu = S * (1.0f / 1024.0f);
      float var = SS * (1.0f / 1024.0f) - mu * mu;
      red[0] = mu; red[1] = rsqrtf(var + 1e-5f);
    }
    __syncthreads();
    const float mu = red[0], rstd = red[1];
    float4 gg = ((const float4*)p.g)[tid];
    float4 bb = ((const float4*)p.b)[tid];
    ushort4 o;
    o.x = f2b((v.x - mu) * rstd * gg.x + bb.x);
    o.y = f2b((v.y - mu) * rstd * gg.y + bb.y);
    o.z = f2b((v.z - mu) * rstd * gg.z + bb.z);
    o.w = f2b((v.w - mu) * rstd * gg.w + bb.w);
    ((ushort4*)(p.normed + (long)row * 1024))[tid] = o;
  }
}

// ---------------------------------------------------------------- reduce 8 bf16 slabs -> bf16
__global__ __launch_bounds__(256) void reduce_cvt(
    const unsigned short* __restrict__ part, unsigned short* __restrict__ out) {
  const int idx = blockIdx.x * 256 + threadIdx.x;   // over 4*65536 ushort4s
  const int b = idx >> 16, i = idx & 65535;
  float4 s = make_float4(0.f, 0.f, 0.f, 0.f);
#pragma unroll
  for (int sl = 0; sl < 8; ++sl) {
    ushort4 v = ((const ushort4*)part)[(long)(b * 8 + sl) * 65536 + i];
    s.x += b2f(v.x); s.y += b2f(v.y); s.z += b2f(v.z); s.w += b2f(v.w);
  }
  ushort4 o;
  o.x = f2b(s.x); o.y = f2b(s.y); o.z = f2b(s.z); o.w = f2b(s.w);
  ((ushort4*)out)[(long)b * 65536 + i] = o;
}

// ---------------------------------------------------------------- GEMM (BT)
enum { EPI_HSPLIT, EPI_ARELU, EPI_PART, EPI_QUADLIN, EPI_FINAL };

struct GemmP {
  const unsigned short* A;
  const unsigned short* B;
  const unsigned short* A2;   // QUADLIN phase-2
  const unsigned short* B2;
  int K, lda, ldb, ldc, mPerZ;
  long aZ, bZ;
  float scale;
  const float* bias;
  const float* bias2;
  const float* xres;
  const float* gamma;         // HSPLIT rope
  const float* beta;
  const unsigned short* gateIn;
  unsigned short* outU;
  unsigned short* gateOut;
  unsigned short* vTout;
  unsigned short* qqO;
  unsigned short* lqO;
  unsigned short* qkhO;
  unsigned short* lkTO;
  float* outF;
};

template <int EPI>
__global__ __launch_bounds__(256, 2) void gemm_bt(GemmP p) {
  constexpr bool kTrV = (EPI == EPI_HSPLIT);
  __shared__ unsigned short As[128 * 32];
  __shared__ unsigned short Bs[128 * 32];
  __shared__ unsigned int Cx[kTrV ? 128 * 68 : 1];  // separate C-tile scratch (R3-proven)

  const int tid = threadIdx.x;
  const int lane = tid & 63;
  const int wave = tid >> 6;
  const int bx = blockIdx.x;
  int by = blockIdx.y;
  // HSPLIT: qk/rope blocks (logical by==32) have the heaviest epilogue —
  // dispatch them FIRST so their tail overlaps the v/gate blocks' K-loops.
  if constexpr (EPI == EPI_HSPLIT) by = (by == 0) ? 32 : by - 1;
  const int z = blockIdx.z;

  unsigned short* lA = As + wave * 32 * 32;
  unsigned short* lB = Bs + wave * 32 * 32;
  const int wm = (wave & 1) * 64;
  const int wn = (wave >> 1) * 64;
  const int lm = lane & 15;
  const int kb = lane >> 4;
  const int rowSel = (wave * 32 + (lane >> 2));   // staging row within 128-tile
  const int colSel = (lane & 3) * 8;              // staging k-offset

  f32x4_t acc[4][4];
#pragma unroll
  for (int i = 0; i < 4; ++i)
#pragma unroll
    for (int j = 0; j < 4; ++j) acc[i][j] = (f32x4_t){0.f, 0.f, 0.f, 0.f};

  auto kloop = [&](const unsigned short* Ag, const unsigned short* Bg,
                   int lda, int ldb, int ksteps) {
    const int a16 = 16 * lda, b16 = 16 * ldb;
    for (int kt = 0; kt < ksteps; ++kt) {
      load_lds16(Ag, lA);
      load_lds16(Ag + a16, lA + 512);
      load_lds16(Bg, lB);
      load_lds16(Bg + b16, lB + 512);
      Ag += 32; Bg += 32;
      __syncthreads();
      bf16x8_t aF[4], bF[4];
#pragma unroll
      for (int i = 0; i < 4; ++i)
        aF[i] = *(const bf16x8_t*)(As + (wm + i * 16 + lm) * 32 + kb * 8);
#pragma unroll
      for (int j = 0; j < 4; ++j)
        bF[j] = *(const bf16x8_t*)(Bs + (wn + j * 16 + lm) * 32 + kb * 8);
#pragma unroll
      for (int i = 0; i < 4; ++i)
#pragma unroll
        for (int j = 0; j < 4; ++j)
          acc[i][j] = __builtin_amdgcn_mfma_f32_16x16x32_bf16(aF[i], bF[j], acc[i][j], 0, 0, 0);
      __syncthreads();
    }
  };

  if constexpr (EPI == EPI_QUADLIN) {
    const int b = z >> 3, g = z & 7;
    // phase 1: attn[z] (M=256 rows, K=256) @ vT[b][:, g*256:+256]
    kloop(p.A + (long)z * p.aZ + (long)(bx * 128 + rowSel) * 256 + colSel,
          p.B + (long)b * p.bZ + (long)(by * 128 + rowSel) * 2048 + g * 256 + colSel,
          256, 2048, 8);
    // phase 2: lin_q rows @ lkvT (K=128)
    kloop(p.A2 + ((long)z * 256 + bx * 128 + rowSel) * 128 + colSel,
          p.B2 + (long)b * 262144 + (long)(by * 128 + rowSel) * 128 + colSel,
          128, 128, 4);
  } else if constexpr (EPI == EPI_PART) {
    const int b = z >> 3, s = z & 7;   // split-K: 8 slices of 256
    kloop(p.A + (long)b * p.aZ + s * 256 + (long)(bx * 128 + rowSel) * p.lda + colSel,
          p.B + (long)b * p.bZ + s * 256 + (long)(by * 128 + rowSel) * p.ldb + colSel,
          p.lda, p.ldb, p.K >> 5);
  } else {
    kloop(p.A + (long)z * p.aZ + (long)(bx * 128 + rowSel) * p.lda + colSel,
          p.B + (long)z * p.bZ + (long)(by * 128 + rowSel) * p.ldb + colSel,
          p.lda, p.ldb, p.K >> 5);
  }

  // ---------------- epilogue ----------------
  if constexpr (EPI == EPI_HSPLIT) {
    if (by < 16) {
      // v half: silu, pack, LDS-transpose, coalesced store into vT[b][e][n]
#pragma unroll
      for (int i = 0; i < 4; ++i) {
        const int m_l = wm + i * 16 + (lane >> 4) * 4;
#pragma unroll
        for (int j = 0; j < 4; ++j) {
          const int e_l = wn + j * 16 + lm;
          const float bb = p.bias[by * 128 + e_l];
          const float s0 = silu_f(acc[i][j][0] + bb);
          const float s1 = silu_f(acc[i][j][1] + bb);
          const float s2 = silu_f(acc[i][j][2] + bb);
          const float s3 = silu_f(acc[i][j][3] + bb);
          Cx[e_l * 68 + (m_l >> 1)] = pack2(s0, s1);
          Cx[e_l * 68 + (m_l >> 1) + 1] = pack2(s2, s3);
        }
      }
      __syncthreads();
      const int b = bx >> 4;
      const int n0 = (bx & 15) * 128;
      unsigned short* dst = p.vTout + ((long)b * 2048 + by * 128) * 2048 + n0;
#pragma unroll
      for (int rep = 0; rep < 8; ++rep) {
        const int flat = rep * 256 + tid;
        const int e_l = flat >> 4, q = flat & 15;
        uint4 val = *(const uint4*)(Cx + e_l * 68 + q * 4);
        *(uint4*)(dst + (long)e_l * 2048 + q * 8) = val;
      }
    } else if (by < 32) {
      // gate half
#pragma unroll
      for (int i = 0; i < 4; ++i) {
        const int row0 = bx * 128 + wm + i * 16 + (lane >> 4) * 4;
#pragma unroll
        for (int j = 0; j < 4; ++j) {
          const int col = by * 128 + wn + j * 16 + lm;   // 2048..4095
          const float bb = p.bias[col];
#pragma unroll
          for (int r = 0; r < 4; ++r)
            p.gateOut[(long)(row0 + r) * 2048 + col - 2048] =
                f2b(silu_f(acc[i][j][r] + bb));
        }
      }
    } else {
      // qk block (all 128 qk dims): silu -> LDS -> OffsetScale+RoPE
      unsigned short* q16 = (unsigned short*)Cx;   // [128][136] bf16 = 34816B
#pragma unroll
      for (int i = 0; i < 4; ++i) {
        const int rloc = wm + i * 16 + (lane >> 4) * 4;
#pragma unroll
        for (int j = 0; j < 4; ++j) {
          const int cl = wn + j * 16 + lm;         // 0..127
          const float bb = p.bias2[cl];
#pragma unroll
          for (int r = 0; r < 4; ++r)
            q16[(rloc + r) * 136 + cl] = f2b(silu_f(acc[i][j][r] + bb));
        }
      }
      __syncthreads();
      const int j = tid & 63;
      const int rq = tid >> 6;
      const float freq = powf(10000.0f, (float)j * (1.0f / 64.0f));
      float ga[4], gb[4], ea[4], eb[4];
#pragma unroll
      for (int h = 0; h < 4; ++h) {
        ga[h] = p.gamma[h * 128 + j];  gb[h] = p.gamma[h * 128 + 64 + j];
        ea[h] = p.beta[h * 128 + j];   eb[h] = p.beta[h * 128 + 64 + j];
      }
      unsigned short* outs[3] = {p.qqO, p.lqO, p.qkhO};
      for (int rr = 0; rr < 32; ++rr) {
        const int row = rr * 4 + rq;
        const float x1 = b2f(q16[row * 136 + j]);
        const float x2 = b2f(q16[row * 136 + 64 + j]);
        const int t = bx * 128 + row;
        const int pos = t & 2047, bidx = t >> 11;
        const float ang = (float)pos * freq;
        const float sn = sinf(ang), cs = cosf(ang);
#pragma unroll
        for (int h = 0; h < 3; ++h) {
          const float y1 = x1 * ga[h] + ea[h], y2 = x2 * gb[h] + eb[h];
          outs[h][(long)t * 128 + j] = f2b(y1 * cs - y2 * sn);
          outs[h][(long)t * 128 + 64 + j] = f2b(y2 * cs + y1 * sn);
        }
        const float y1 = x1 * ga[3] + ea[3], y2 = x2 * gb[3] + eb[3];
        p.lkTO[((long)bidx * 128 + j) * 2048 + pos] = f2b(y1 * cs - y2 * sn);
        p.lkTO[((long)bidx * 128 + 64 + j) * 2048 + pos] = f2b(y2 * cs + y1 * sn);
      }
    }
  } else {
#pragma unroll
    for (int i = 0; i < 4; ++i) {
      const int row0 = bx * 128 + wm + i * 16 + (lane >> 4) * 4;
      long rowg0;
      if constexpr (EPI == EPI_PART) rowg0 = row0;           // within-slab row
      else rowg0 = (long)z * p.mPerZ + row0;
#pragma unroll
      for (int j = 0; j < 4; ++j) {
        const int col = by * 128 + wn + j * 16 + lm;
        if constexpr (EPI == EPI_ARELU) {
#pragma unroll
          for (int r = 0; r < 4; ++r) {
            float s = acc[i][j][r] * p.scale;
            s = s > 0.f ? s : 0.f;
            p.outU[(rowg0 + r) * (long)p.ldc + col] = f2b(s * s);
          }
        } else if constexpr (EPI == EPI_PART) {
          unsigned short* slab = p.outU + (long)z * 262144;  // z = b*8+s
#pragma unroll
          for (int r = 0; r < 4; ++r)
            slab[(rowg0 + r) * (long)p.ldc + col] = f2b(acc[i][j][r] * p.scale);
        } else if constexpr (EPI == EPI_QUADLIN) {
#pragma unroll
          for (int r = 0; r < 4; ++r) {
            const long idx = (rowg0 + r) * (long)p.ldc + col;
            p.outU[idx] = f2b(b2f(p.gateIn[idx]) * acc[i][j][r]);
          }
        } else {  // EPI_FINAL: + b_out + x residual, fp32 out
          const float bb = p.bias[col];
#pragma unroll
          for (int r = 0; r < 4; ++r) {
            const long idx = (rowg0 + r) * (long)p.ldc + col;
            p.outF[idx] = acc[i][j][r] + bb + p.xres[idx];
          }
        }
      }
    }
  }
}

// ---------------------------------------------------------------- launch
extern "C" void kernel_launch(void* const* d_in, const int* in_sizes, int n_in,
                              void* d_out, int out_size, void* d_ws, size_t ws_size,
                              hipStream_t stream) {
  const float* x        = (const float*)d_in[0];
  const float* ln_g     = (const float*)d_in[1];
  const float* ln_b     = (const float*)d_in[2];
  const float* W_hidden = (const float*)d_in[3];
  const float* b_hidden = (const float*)d_in[4];
  const float* W_qk     = (const float*)d_in[5];
  const float* b_qk     = (const float*)d_in[6];
  const float* os_gamma = (const float*)d_in[7];
  const float* os_beta  = (const float*)d_in[8];
  const float* W_out    = (const float*)d_in[9];
  const float* b_out    = (const float*)d_in[10];
  float* out = (float*)d_out;

  char* w = (char*)d_ws;
  auto ws = [&](size_t bytes) { char* p = w; w += bytes; return (unsigned short*)p; };
  unsigned short* WT     = ws(8650752);   // [4224][1024] bf16 (Wh cols | Wqk cols)
  unsigned short* WoT    = ws(4194304);   // [1024][2048]
  unsigned short* normed = ws(16777216);  // [8192][1024]
  unsigned short* vT     = ws(33554432);  // [4][2048 e][2048 n]
  unsigned short* gate   = ws(33554432);  // [8192][2048]
  unsigned short* qq     = ws(2097152);
  unsigned short* qkh    = ws(2097152);
  unsigned short* lq     = ws(2097152);
  unsigned short* lkT    = ws(2097152);   // [4][128][2048]
  unsigned short* attn   = ws(4194304);   // [32][256][256]
  unsigned short* lkvP   = ws(16777216);  // [32 slabs][2048][128] bf16 partials
  unsigned short* lkvT   = ws(2097152);   // [4][2048 e][128 d] bf16
  unsigned short* A3     = ws(33554432);  // [8192][2048]

  {  // weight transposes + layernorm in one dispatch
    PrepP p{W_hidden, W_out, W_qk, x, ln_g, ln_b, WT, WoT, normed};
    prep_kernel<<<14464, 256, 0, stream>>>(p);
  }
  {  // GEMM1: [v->vT | gate | qk->rope(qq,lq,qkh,lkT)] = silu(normed @ [Wh|Wqk] + b)
    GemmP p{}; p.A = normed; p.B = WT; p.K = 1024; p.lda = 1024; p.ldb = 1024;
    p.bias = b_hidden; p.bias2 = b_qk;
    p.gamma = os_gamma; p.beta = os_beta;
    p.vTout = vT; p.gateOut = gate;
    p.qqO = qq; p.lqO = lq; p.qkhO = qkh; p.lkTO = lkT;
    gemm_bt<EPI_HSPLIT><<<dim3(64, 33, 1), 256, 0, stream>>>(p);
  }
  {  // sim -> attn = relu(sim/256)^2, per (b,g)
    GemmP p{}; p.A = qq; p.B = qkh; p.K = 128; p.lda = 128; p.ldb = 128;
    p.ldc = 256; p.mPerZ = 256; p.aZ = 32768; p.bZ = 32768;
    p.scale = 1.f / 256.f; p.outU = attn;
    gemm_bt<EPI_ARELU><<<dim3(2, 2, 32), 256, 0, stream>>>(p);
  }
  {  // lin_kv partials: slab[z=b*8+s][e][d] = vT[b][e][sK] @ lkT[b][d][sK] / 2048
    GemmP p{}; p.A = vT; p.B = lkT; p.K = 256; p.lda = 2048; p.ldb = 2048;
    p.ldc = 128; p.mPerZ = 2048; p.aZ = 4194304; p.bZ = 262144;
    p.scale = 1.f / 2048.f; p.outU = lkvP;
    gemm_bt<EPI_PART><<<dim3(16, 1, 32), 256, 0, stream>>>(p);
  }
  reduce_cvt<<<1024, 256, 0, stream>>>(lkvP, lkvT);
  {  // A3 = gate * (attn @ vg + lin_q @ lin_kv)   (two-phase K)
    GemmP p{}; p.A = attn; p.B = vT; p.A2 = lq; p.B2 = lkvT;
    p.ldc = 2048; p.mPerZ = 256; p.aZ = 65536; p.bZ = 4194304;
    p.gateIn = gate; p.outU = A3;
    gemm_bt<EPI_QUADLIN><<<dim3(2, 16, 32), 256, 0, stream>>>(p);
  }
  {  // out = A3 @ W_out + b_out + x
    GemmP p{}; p.A = A3; p.B = WoT; p.K = 2048; p.lda = 2048; p.ldb = 2048;
    p.ldc = 1024; p.mPerZ = 0; p.bias = b_out; p.xres = x; p.outF = out;
    gemm_bt<EPI_FINAL><<<dim3(64, 8, 1), 256, 0, stream>>>(p);
  }
}